// Round 5
// baseline (207.757 us; speedup 1.0000x reference)
//
#include <hip/hip_runtime.h>
#include <hip/hip_bf16.h>

typedef __attribute__((ext_vector_type(8))) short bf16x8;   // 8 bf16 = 4 VGPRs
typedef __attribute__((ext_vector_type(4))) float f32x4;
typedef unsigned short u16t;

#define DEVINL static __device__ __forceinline__

DEVINL u16t f2bf(float f) {
  union { __hip_bfloat16 h; u16t u; } cv;
  cv.h = __float2bfloat16(f);
  return cv.u;
}

// packed f32x2 -> bf16x2 (dst.lo = cvt(a), dst.hi = cvt(b)); no builtin on gfx950
DEVINL unsigned cvt_pk_bf16(float a, float b) {
  unsigned r;
  asm("v_cvt_pk_bf16_f32 %0, %1, %2" : "=v"(r) : "v"(a), "v"(b));
  return r;
}

DEVINL void async16(void* lds, const void* g) {
  __builtin_amdgcn_global_load_lds((const __attribute__((address_space(1))) void*)g,
                                   (__attribute__((address_space(3))) void*)lds,
                                   16, 0, 0);
}

// ---------------------------------------------------------------------------
// fp32 -> bf16 conversion for x (4M elems) + Wq/Wk/Wv/Wo (1M each).
// Wq/Wk/Wv destinations are CONTIGUOUS -> later treated as one [3072][1024].
// ---------------------------------------------------------------------------
__global__ __launch_bounds__(256) void convert_bf16(
    const float* __restrict__ x,  const float* __restrict__ wq,
    const float* __restrict__ wk, const float* __restrict__ wv,
    const float* __restrict__ wo,
    u16t* __restrict__ xb, u16t* __restrict__ wqb, u16t* __restrict__ wkb,
    u16t* __restrict__ wvb, u16t* __restrict__ wob) {
  const int blk = blockIdx.x;
  const float* src; u16t* dst; size_t off;
  if (blk < 4096)      { src = x;  dst = xb;  off = (size_t)blk * 1024; }
  else if (blk < 5120) { src = wq; dst = wqb; off = (size_t)(blk - 4096) * 1024; }
  else if (blk < 6144) { src = wk; dst = wkb; off = (size_t)(blk - 5120) * 1024; }
  else if (blk < 7168) { src = wv; dst = wvb; off = (size_t)(blk - 6144) * 1024; }
  else                 { src = wo; dst = wob; off = (size_t)(blk - 7168) * 1024; }
  const size_t i = off + (size_t)threadIdx.x * 4;
  const float4 v = *(const float4*)&src[i];
  ushort4 r;
  r.x = f2bf(v.x); r.y = f2bf(v.y); r.z = f2bf(v.z); r.w = f2bf(v.w);
  *(ushort4*)&dst[i] = r;
}

// ---------------------------------------------------------------------------
// C[m,n] = sum_k A[m,k]*B[n,k].  A:[M,K], B:[N,K] row-major bf16.
// BK=64 as TWO m97-style BK=32 panels. MODE 0: C0 row-major [M,N] fp32.
// MODE 1 (fused QKV, N=3072), nz = n0>>10:
//   nz==0 (Q): head-split bf16, PRE-SCALED by 0.125/ln2 (softmax fold)
//   nz==1 (K): frag-tiled: ((t>>4)*8+(d>>3))*128 + (t&15)*8 + (d&7)
//   nz==2 (V): frag-tiled: ((d>>4)*256+(t>>3))*128 + (d&15)*8 + (t&7)
// ---------------------------------------------------------------------------
template <int MODE>
__global__ __launch_bounds__(256) void gemm_bt(
    const u16t* __restrict__ A, const u16t* __restrict__ B,
    void* __restrict__ C0, void* __restrict__ C1, void* __restrict__ C2,
    int M, int N, int K) {
  __shared__ u16t As[2][128 * 32];
  __shared__ u16t Bs[2][128 * 32];

  const int tid = threadIdx.x;
  const int lane = tid & 63;
  const int w = tid >> 6;
  const int wm = w >> 1, wn = w & 1;
  const int quad = lane >> 4, cl = lane & 15;
  const int m0 = blockIdx.y * 128;
  const int n0 = blockIdx.x * 128;

  const int srow = lane >> 2;        // row within 16-row staging chunk
  const int scol = (lane & 3) * 8;   // 8-elem (16B) column chunk

  f32x4 acc[4][4] = {};

  for (int k0 = 0; k0 < K; k0 += 64) {
    __syncthreads();
    #pragma unroll
    for (int p = 0; p < 2; ++p)
      #pragma unroll
      for (int ii = 0; ii < 2; ++ii) {
        const int c = w + ii * 4;    // chunk 0..7 (16 rows each)
        async16(&As[p][c * 512], &A[(size_t)(m0 + c * 16 + srow) * K + k0 + p * 32 + scol]);
        async16(&Bs[p][c * 512], &B[(size_t)(n0 + c * 16 + srow) * K + k0 + p * 32 + scol]);
      }
    __syncthreads();                 // compiler drains vmcnt before s_barrier
    #pragma unroll
    for (int p = 0; p < 2; ++p) {
      bf16x8 af[4], bfr[4];
      #pragma unroll
      for (int i = 0; i < 4; ++i)
        af[i] = *(const bf16x8*)&As[p][(wm * 64 + i * 16 + cl) * 32 + quad * 8];
      #pragma unroll
      for (int j = 0; j < 4; ++j)
        bfr[j] = *(const bf16x8*)&Bs[p][(wn * 64 + j * 16 + cl) * 32 + quad * 8];
      #pragma unroll
      for (int i = 0; i < 4; ++i)
        #pragma unroll
        for (int j = 0; j < 4; ++j)
          acc[i][j] = __builtin_amdgcn_mfma_f32_16x16x32_bf16(af[i], bfr[j], acc[i][j], 0, 0, 0);
    }
  }

  const int nz = n0 >> 10;           // MODE1: weight id (block-uniform)
  #pragma unroll
  for (int i = 0; i < 4; ++i)
    #pragma unroll
    for (int j = 0; j < 4; ++j) {
      const int mb = m0 + wm * 64 + i * 16 + quad * 4;   // 4 consecutive m (t)
      const int n  = n0 + wn * 64 + j * 16 + cl;
      if (MODE == 0) {
        #pragma unroll
        for (int r = 0; r < 4; ++r)
          ((float*)C0)[(size_t)(mb + r) * N + n] = acc[i][j][r];
      } else {
        const int nw = n & 1023, h = nw >> 6, d = nw & 63;
        const int b = mb >> 11, tb = mb & 2047;
        const size_t bh = (size_t)(b * 16 + h);
        if (nz == 2) {
          ushort4 v4;
          v4.x = f2bf(acc[i][j][0]); v4.y = f2bf(acc[i][j][1]);
          v4.z = f2bf(acc[i][j][2]); v4.w = f2bf(acc[i][j][3]);
          const size_t addr = (bh << 17) +
              (size_t)(((d >> 4) * 256 + (tb >> 3)) * 128 + (d & 15) * 8 + (tb & 7));
          *(ushort4*)&((u16t*)C2)[addr] = v4;
        } else if (nz == 1) {
          const size_t basea = (bh << 17) +
              (size_t)(((tb >> 4) * 8 + (d >> 3)) * 128 + (d & 7));
          #pragma unroll
          for (int r = 0; r < 4; ++r)
            ((u16t*)C1)[basea + ((tb & 15) + r) * 8] = f2bf(acc[i][j][r]);
        } else {
          // Q: pre-scale by 0.125/ln2 so flash softmax is p = exp2(s)
          #pragma unroll
          for (int r = 0; r < 4; ++r)
            ((u16t*)C0)[(bh * 2048 + tb + r) * 64 + d] =
                f2bf(acc[i][j][r] * 0.18033688011112043f);
        }
      }
    }
}

// ---------------------------------------------------------------------------
// Flash attention V6: block-shared K/V LDS staging, 2-phase double-buffer
// (GEMM T3-min template), 64-key tiles, 16 q-rows/wave, bh-pinned XCDs.
// Grid (x=32 bh, y=32 q-chunks), block 256 = 4 waves (64 q-rows/block).
//
//  - Per tile (64 keys): K tile 8 KB + V tile 8 KB staged ONCE per block
//    into LDS dbuf via global_load_lds (16B), issued for tile t+1 BEFORE
//    computing tile t; one __syncthreads per tile (drains vmcnt).
//    Cuts per-wave global K/V reads 4x; hot loop reads are ds_read_b128,
//    conflict-free (consecutive lanes -> consecutive 16B).
//  - Kt tile is a CONTIGUOUS 4096-elem slab (jt*4096); Vt tile is 4
//    contiguous 1024-elem chunks (per ds) -> staging is linear copies.
//  - Swapped QK^T: s = mfma(K,Q) -> lane holds P[q=cl][k=js*16+quad*4+r].
//  - P scratch per wave 16 rows x stride 72 u16 (144 B): b64 writes
//    (4 lanes/bank) and b128 reads (8 lanes/bank) both exactly minimal;
//    16B-aligned. Same-wave write->read ordered by lgkmcnt, no barrier.
//  - Row sums via ones-MFMA; rows align with O rows -> lane-local rcp.
//  - setprio(1) around MFMA clusters (T5; phase-diverse schedule now).
// No online max (scores pre-scaled, exp2 arg |.| small, fp32-safe).
// LDS: 2*8K (K) + 2*8K (V) + 9.2K (P) = 42 KB -> 3 blocks/CU, 12 waves/CU.
// ---------------------------------------------------------------------------
__global__ __launch_bounds__(256) void flash_attn(
    const u16t* __restrict__ Q, const u16t* __restrict__ Kt,
    const u16t* __restrict__ Vt, u16t* __restrict__ Y) {
  __shared__ u16t Ks[2][4096];        // [buf][64 keys x 64 d], frag-tiled order
  __shared__ u16t Vs[2][4096];        // [buf][4 ds-chunks x 1024]
  __shared__ u16t Ps[4][16 * 72];     // per-wave P scratch, stride 72

  const int tid = threadIdx.x;
  const int lane = tid & 63;
  const int w = tid >> 6;
  const int quad = lane >> 4, cl = lane & 15;
  const int bh = blockIdx.x;          // bh on x: id%8==bh%8 pins bh to one XCD
  const int q0 = blockIdx.y * 64 + w * 16;
  const u16t* Kb = Kt + ((size_t)bh << 17);
  const u16t* Vb = Vt + ((size_t)bh << 17);

  // Q fragments tile-invariant in registers (row q0+cl, k=ks*32+quad*8+j)
  bf16x8 aq[2];
  #pragma unroll
  for (int ks = 0; ks < 2; ++ks)
    aq[ks] = *(const bf16x8*)&Q[((size_t)bh * 2048 + q0 + cl) * 64 + ks * 32 + quad * 8];

  bf16x8 ones8;                       // bf16 1.0 splat for row-sum MFMA
  #pragma unroll
  for (int i = 0; i < 8; ++i) ones8[i] = (short)0x3F80;

  f32x4 o[4] = {};                    // O acc: row=quad*4+r (q), col=ds*16+cl (d)
  f32x4 psum = {};                    // row sums, same row mapping as o

  u16t* Pw = &Ps[w][0];

  // stage tile jt into buffer b: wave w moves K chunks 2w,2w+1 and V
  // chunks 2w,2w+1 (each 512 elems = 1 KB; lane-linear 16B units)
  #define STAGE(b, jt)                                                        \
    {                                                                         \
      _Pragma("unroll")                                                       \
      for (int c = 0; c < 2; ++c) {                                           \
        const int ch = w * 2 + c;                                             \
        async16(&Ks[b][ch * 512],                                             \
                &Kb[(size_t)(jt) * 4096 + ch * 512 + lane * 8]);              \
        async16(&Vs[b][ch * 512],                                             \
                &Vb[(size_t)(ch >> 1) * 32768 + (size_t)(jt) * 1024 +         \
                    (ch & 1) * 512 + lane * 8]);                              \
      }                                                                       \
    }

  STAGE(0, 0);
  __syncthreads();                    // drains vmcnt -> tile 0 resident

  #pragma unroll 2
  for (int jt = 0; jt < 32; ++jt) {
    const int buf = jt & 1;
    if (jt + 1 < 32) STAGE(buf ^ 1, jt + 1);   // prefetch flies under compute

    // S^T = K Q^T from LDS : lane holds P[q=cl][k=js*16+quad*4+(0..3)]
    f32x4 s[4] = {};
    __builtin_amdgcn_s_setprio(1);
    #pragma unroll
    for (int ks = 0; ks < 2; ++ks) {
      bf16x8 kf[4];
      #pragma unroll
      for (int js = 0; js < 4; ++js)
        kf[js] = *(const bf16x8*)&Ks[buf][(js * 8 + ks * 4) * 128 + lane * 8];
      #pragma unroll
      for (int js = 0; js < 4; ++js)
        s[js] = __builtin_amdgcn_mfma_f32_16x16x32_bf16(kf[js], aq[ks], s[js], 0, 0, 0);
    }
    __builtin_amdgcn_s_setprio(0);

    // p = exp2(s); pack 4 consecutive k -> one b64 write per js
    #pragma unroll
    for (int js = 0; js < 4; ++js) {
      uint2 pk;
      pk.x = cvt_pk_bf16(__builtin_exp2f(s[js][0]), __builtin_exp2f(s[js][1]));
      pk.y = cvt_pk_bf16(__builtin_exp2f(s[js][2]), __builtin_exp2f(s[js][3]));
      *(uint2*)&Pw[cl * 72 + js * 16 + quad * 4] = pk;
    }
    // same-wave LDS write->read ordered by lgkmcnt (no barrier)

    // O += P @ V from LDS ; row sums via ones-MFMA on the same A-frag
    __builtin_amdgcn_s_setprio(1);
    #pragma unroll
    for (int ks = 0; ks < 2; ++ks) {
      const bf16x8 ap = *(const bf16x8*)&Pw[cl * 72 + ks * 32 + quad * 8];
      bf16x8 vf[4];
      #pragma unroll
      for (int ds = 0; ds < 4; ++ds)
        vf[ds] = *(const bf16x8*)&Vs[buf][ds * 1024 + ks * 512 + lane * 8];
      psum = __builtin_amdgcn_mfma_f32_16x16x32_bf16(ap, ones8, psum, 0, 0, 0);
      #pragma unroll
      for (int ds = 0; ds < 4; ++ds)
        o[ds] = __builtin_amdgcn_mfma_f32_16x16x32_bf16(ap, vf[ds], o[ds], 0, 0, 0);
    }
    __builtin_amdgcn_s_setprio(0);

    __syncthreads();                  // stage(jt+1) landed; buf free for reuse
  }
  #undef STAGE

  // psum rows align with o rows: lane-local normalize, no shuffles
  float inv[4];
  #pragma unroll
  for (int r = 0; r < 4; ++r) inv[r] = __builtin_amdgcn_rcpf(psum[r]);

  const int b = bh >> 4, hd = bh & 15;
  #pragma unroll
  for (int ds = 0; ds < 4; ++ds)
    #pragma unroll
    for (int r = 0; r < 4; ++r) {
      const int t = q0 + quad * 4 + r;
      const int d = ds * 16 + cl;
      Y[((size_t)b * 2048 + t) * 1024 + hd * 64 + d] = f2bf(o[ds][r] * inv[r]);
    }
}

extern "C" void kernel_launch(void* const* d_in, const int* in_sizes, int n_in,
                              void* d_out, int out_size, void* d_ws, size_t ws_size,
                              hipStream_t stream) {
  (void)in_sizes; (void)n_in; (void)out_size; (void)ws_size;
  const float* x  = (const float*)d_in[0];
  const float* Wq = (const float*)d_in[1];
  const float* Wk = (const float*)d_in[2];
  const float* Wv = (const float*)d_in[3];
  const float* Wo = (const float*)d_in[4];

  char* ws = (char*)d_ws;
  const size_t MB = 1024 * 1024;
  u16t* xb  = (u16t*)(ws);               // [4096][1024] bf16 (8 MB) — aliased by Yw
  u16t* Wqb = (u16t*)(ws + 8 * MB);      // Wq/Wk/Wv contiguous -> [3072][1024]
  u16t* Wkb = (u16t*)(ws + 10 * MB);
  u16t* Wvb = (u16t*)(ws + 12 * MB);
  u16t* Wob = (u16t*)(ws + 14 * MB);
  u16t* Qw  = (u16t*)(ws + 16 * MB);     // [32][2048][64] bf16 head-split (pre-scaled)
  u16t* Ktw = (u16t*)(ws + 24 * MB);     // [32] fragment-tiled K'
  u16t* Vtw = (u16t*)(ws + 32 * MB);     // [32] fragment-tiled V'
  u16t* Yw  = xb;                        // safe alias: xb dead after QKV gemm

  convert_bf16<<<8192, 256, 0, stream>>>(x, Wq, Wk, Wv, Wo, xb, Wqb, Wkb, Wvb, Wob);
  // fused QKV: B = [3072][1024], output target selected by n0>>10
  gemm_bt<1><<<dim3(24, 32), 256, 0, stream>>>(
      xb, Wqb, Qw, Ktw, Vtw, 4096, 3072, 1024);
  flash_attn<<<dim3(32, 32), 256, 0, stream>>>(Qw, Ktw, Vtw, Yw);
  gemm_bt<0><<<dim3(8, 32), 256, 0, stream>>>(
      Yw, Wob, d_out, d_out, d_out, 4096, 1024, 1024);
}

// Round 6
// 204.855 us; speedup vs baseline: 1.0142x; 1.0142x over previous
//
#include <hip/hip_runtime.h>
#include <hip/hip_bf16.h>

typedef __attribute__((ext_vector_type(8))) short bf16x8;   // 8 bf16 = 4 VGPRs
typedef __attribute__((ext_vector_type(4))) float f32x4;
typedef unsigned short u16t;

#define DEVINL static __device__ __forceinline__

DEVINL u16t f2bf(float f) {
  union { __hip_bfloat16 h; u16t u; } cv;
  cv.h = __float2bfloat16(f);
  return cv.u;
}

// packed f32x2 -> bf16x2 (dst.lo = cvt(a), dst.hi = cvt(b)); no builtin on gfx950
DEVINL unsigned cvt_pk_bf16(float a, float b) {
  unsigned r;
  asm("v_cvt_pk_bf16_f32 %0, %1, %2" : "=v"(r) : "v"(a), "v"(b));
  return r;
}

DEVINL void async16(void* lds, const void* g) {
  __builtin_amdgcn_global_load_lds((const __attribute__((address_space(1))) void*)g,
                                   (__attribute__((address_space(3))) void*)lds,
                                   16, 0, 0);
}

// ---------------------------------------------------------------------------
// fp32 -> bf16 conversion for x (4M elems) + Wq/Wk/Wv/Wo (1M each).
// Wq/Wk/Wv destinations are CONTIGUOUS -> later treated as one [3072][1024].
// ---------------------------------------------------------------------------
__global__ __launch_bounds__(256) void convert_bf16(
    const float* __restrict__ x,  const float* __restrict__ wq,
    const float* __restrict__ wk, const float* __restrict__ wv,
    const float* __restrict__ wo,
    u16t* __restrict__ xb, u16t* __restrict__ wqb, u16t* __restrict__ wkb,
    u16t* __restrict__ wvb, u16t* __restrict__ wob) {
  const int blk = blockIdx.x;
  const float* src; u16t* dst; size_t off;
  if (blk < 4096)      { src = x;  dst = xb;  off = (size_t)blk * 1024; }
  else if (blk < 5120) { src = wq; dst = wqb; off = (size_t)(blk - 4096) * 1024; }
  else if (blk < 6144) { src = wk; dst = wkb; off = (size_t)(blk - 5120) * 1024; }
  else if (blk < 7168) { src = wv; dst = wvb; off = (size_t)(blk - 6144) * 1024; }
  else                 { src = wo; dst = wob; off = (size_t)(blk - 7168) * 1024; }
  const size_t i = off + (size_t)threadIdx.x * 4;
  const float4 v = *(const float4*)&src[i];
  ushort4 r;
  r.x = f2bf(v.x); r.y = f2bf(v.y); r.z = f2bf(v.z); r.w = f2bf(v.w);
  *(ushort4*)&dst[i] = r;
}

// ---------------------------------------------------------------------------
// C[m,n] = sum_k A[m,k]*B[n,k].  A:[M,K], B:[N,K] row-major bf16.
// BK=64 as TWO m97-style BK=32 panels. MODE 0: C0 row-major [M,N] fp32.
// MODE 1 (fused QKV, N=3072), nz = n0>>10:
//   nz==0 (Q): head-split bf16, PRE-SCALED by 0.125/ln2 (softmax fold)
//   nz==1 (K): frag-tiled: ((t>>4)*8+(d>>3))*128 + (t&15)*8 + (d&7)
//   nz==2 (V): frag-tiled: ((d>>4)*256+(t>>3))*128 + (d&15)*8 + (t&7)
// ---------------------------------------------------------------------------
template <int MODE>
__global__ __launch_bounds__(256) void gemm_bt(
    const u16t* __restrict__ A, const u16t* __restrict__ B,
    void* __restrict__ C0, void* __restrict__ C1, void* __restrict__ C2,
    int M, int N, int K) {
  __shared__ u16t As[2][128 * 32];
  __shared__ u16t Bs[2][128 * 32];

  const int tid = threadIdx.x;
  const int lane = tid & 63;
  const int w = tid >> 6;
  const int wm = w >> 1, wn = w & 1;
  const int quad = lane >> 4, cl = lane & 15;
  const int m0 = blockIdx.y * 128;
  const int n0 = blockIdx.x * 128;

  const int srow = lane >> 2;        // row within 16-row staging chunk
  const int scol = (lane & 3) * 8;   // 8-elem (16B) column chunk

  f32x4 acc[4][4] = {};

  for (int k0 = 0; k0 < K; k0 += 64) {
    __syncthreads();
    #pragma unroll
    for (int p = 0; p < 2; ++p)
      #pragma unroll
      for (int ii = 0; ii < 2; ++ii) {
        const int c = w + ii * 4;    // chunk 0..7 (16 rows each)
        async16(&As[p][c * 512], &A[(size_t)(m0 + c * 16 + srow) * K + k0 + p * 32 + scol]);
        async16(&Bs[p][c * 512], &B[(size_t)(n0 + c * 16 + srow) * K + k0 + p * 32 + scol]);
      }
    __syncthreads();                 // compiler drains vmcnt before s_barrier
    #pragma unroll
    for (int p = 0; p < 2; ++p) {
      bf16x8 af[4], bfr[4];
      #pragma unroll
      for (int i = 0; i < 4; ++i)
        af[i] = *(const bf16x8*)&As[p][(wm * 64 + i * 16 + cl) * 32 + quad * 8];
      #pragma unroll
      for (int j = 0; j < 4; ++j)
        bfr[j] = *(const bf16x8*)&Bs[p][(wn * 64 + j * 16 + cl) * 32 + quad * 8];
      #pragma unroll
      for (int i = 0; i < 4; ++i)
        #pragma unroll
        for (int j = 0; j < 4; ++j)
          acc[i][j] = __builtin_amdgcn_mfma_f32_16x16x32_bf16(af[i], bfr[j], acc[i][j], 0, 0, 0);
    }
  }

  const int nz = n0 >> 10;           // MODE1: weight id (block-uniform)
  #pragma unroll
  for (int i = 0; i < 4; ++i)
    #pragma unroll
    for (int j = 0; j < 4; ++j) {
      const int mb = m0 + wm * 64 + i * 16 + quad * 4;   // 4 consecutive m (t)
      const int n  = n0 + wn * 64 + j * 16 + cl;
      if (MODE == 0) {
        #pragma unroll
        for (int r = 0; r < 4; ++r)
          ((float*)C0)[(size_t)(mb + r) * N + n] = acc[i][j][r];
      } else {
        const int nw = n & 1023, h = nw >> 6, d = nw & 63;
        const int b = mb >> 11, tb = mb & 2047;
        const size_t bh = (size_t)(b * 16 + h);
        if (nz == 2) {
          ushort4 v4;
          v4.x = f2bf(acc[i][j][0]); v4.y = f2bf(acc[i][j][1]);
          v4.z = f2bf(acc[i][j][2]); v4.w = f2bf(acc[i][j][3]);
          const size_t addr = (bh << 17) +
              (size_t)(((d >> 4) * 256 + (tb >> 3)) * 128 + (d & 15) * 8 + (tb & 7));
          *(ushort4*)&((u16t*)C2)[addr] = v4;
        } else if (nz == 1) {
          const size_t basea = (bh << 17) +
              (size_t)(((tb >> 4) * 8 + (d >> 3)) * 128 + (d & 7));
          #pragma unroll
          for (int r = 0; r < 4; ++r)
            ((u16t*)C1)[basea + ((tb & 15) + r) * 8] = f2bf(acc[i][j][r]);
        } else {
          // Q: pre-scale by 0.125/ln2 so flash softmax is p = exp2(s)
          #pragma unroll
          for (int r = 0; r < 4; ++r)
            ((u16t*)C0)[(bh * 2048 + tb + r) * 64 + d] =
                f2bf(acc[i][j][r] * 0.18033688011112043f);
        }
      }
    }
}

// ---------------------------------------------------------------------------
// Flash attention V7 = R4 structure (barrier-free, 32 q-rows/wave, bh-pinned
// XCD mapping, register-direct K/V from L2) + deep in-wave pipelining.
// Grid (x=32 bh, y=16 q-chunks), block 256 = 4 independent waves.
//
// Latency-bound at 2 waves/SIMD (grid-capped) -> hide latency with ILP:
//  - Cross-tile K register double-buffer (kA/kB, unrolled-by-2 loop, no
//    runtime-indexed copies): tile t+1's 16 K b128 loads issue right after
//    tile t's P-writes and land under PV (~400 cy cover).
//  - All 16 V b128 loads for tile t issue BEFORE the K-prefetch (in-order
//    vmcnt: PV's vf waits then never force the kn drain), covered by the
//    exp2/cvt/P-write phase.
//  - setprio(1) around QK/PV MFMA clusters (independent-wave regime).
//  - Swapped QK^T: s = mfma(K,Q) -> lane holds P[q=cl][k=js*16+quad*4+r].
//  - P scratch stride 136 u16 (b64-write/b128-read occupancy minimal).
//  - Row sums via ones-MFMA; rows align with O rows -> lane-local rcp.
// No online max (scores pre-scaled, exp2 arg |.| small, fp32-safe).
// VGPR ~210 peak; __launch_bounds__(256,2) caps at 256 (8 waves/CU free).
// ---------------------------------------------------------------------------
__global__ __launch_bounds__(256, 2) void flash_attn(
    const u16t* __restrict__ Q, const u16t* __restrict__ Kt,
    const u16t* __restrict__ Vt, u16t* __restrict__ Y) {
  __shared__ u16t Ps[4][32 * 136];    // per-wave 32-row P scratch (34.8 KB)
  const int tid = threadIdx.x;
  const int lane = tid & 63;
  const int w = tid >> 6;
  const int quad = lane >> 4, cl = lane & 15;
  const int bh = blockIdx.x;          // bh on x: id%8==bh%8 pins bh to one XCD
  const int q0 = blockIdx.y * 128 + w * 32;
  const u16t* Kb = Kt + ((size_t)bh << 17);
  const u16t* Vb = Vt + ((size_t)bh << 17);

  // Q fragments for both halves, tile-invariant (row q0+16h+cl, k=ks*32+quad*8+j)
  bf16x8 aq[2][2];
  #pragma unroll
  for (int h = 0; h < 2; ++h)
    #pragma unroll
    for (int ks = 0; ks < 2; ++ks)
      aq[h][ks] = *(const bf16x8*)&Q[((size_t)bh * 2048 + q0 + 16 * h + cl) * 64 + ks * 32 + quad * 8];

  bf16x8 ones8;                       // bf16 1.0 splat for row-sum MFMA
  #pragma unroll
  for (int i = 0; i < 8; ++i) ones8[i] = (short)0x3F80;

  f32x4 o[2][4] = {};                 // [half][ds]: row=quad*4+r, col=ds*16+cl
  f32x4 psum[2] = {};                 // row sums, same row mapping as o

  u16t* Pw = &Ps[w][0];               // half1 rows at +16*136

  // K register double-buffer: frag (ks,js) of tile jt at
  // Kb[(jt*64 + js*8 + ks*4)*128 + lane*8]
  bf16x8 kA[2][8], kB[2][8];
  #pragma unroll
  for (int ks = 0; ks < 2; ++ks)
    #pragma unroll
    for (int js = 0; js < 8; ++js)
      kA[ks][js] = *(const bf16x8*)&Kb[(size_t)((js * 8 + ks * 4) * 128) + lane * 8];

  // One 128-key tile: compute with kc, prefetch tile jt+1 into kn.
  #define TILE_STEP(jt, kc, kn)                                               \
  {                                                                           \
    /* QK: S^T = K Q^T; lane holds P[q=cl][k=js*16+quad*4+(0..3)] */          \
    f32x4 s0[8] = {}, s1[8] = {};                                             \
    __builtin_amdgcn_s_setprio(1);                                            \
    _Pragma("unroll")                                                         \
    for (int ks = 0; ks < 2; ++ks) {                                          \
      _Pragma("unroll")                                                       \
      for (int js = 0; js < 8; ++js)                                          \
        s0[js] = __builtin_amdgcn_mfma_f32_16x16x32_bf16(kc[ks][js], aq[0][ks], s0[js], 0, 0, 0); \
      _Pragma("unroll")                                                       \
      for (int js = 0; js < 8; ++js)                                          \
        s1[js] = __builtin_amdgcn_mfma_f32_16x16x32_bf16(kc[ks][js], aq[1][ks], s1[js], 0, 0, 0); \
    }                                                                         \
    __builtin_amdgcn_s_setprio(0);                                            \
    /* p = exp2(s); pack 4 consecutive k -> one b64 write per (half, js) */   \
    _Pragma("unroll")                                                         \
    for (int js = 0; js < 8; ++js) {                                          \
      uint2 pk0, pk1;                                                         \
      pk0.x = cvt_pk_bf16(__builtin_exp2f(s0[js][0]), __builtin_exp2f(s0[js][1])); \
      pk0.y = cvt_pk_bf16(__builtin_exp2f(s0[js][2]), __builtin_exp2f(s0[js][3])); \
      *(uint2*)&Pw[cl * 136 + js * 16 + quad * 4] = pk0;                      \
      pk1.x = cvt_pk_bf16(__builtin_exp2f(s1[js][0]), __builtin_exp2f(s1[js][1])); \
      pk1.y = cvt_pk_bf16(__builtin_exp2f(s1[js][2]), __builtin_exp2f(s1[js][3])); \
      *(uint2*)&Pw[(16 + cl) * 136 + js * 16 + quad * 4] = pk1;               \
    }                                                                         \
    /* all 16 V b128 loads up-front (fly under exp2 already issued above,    \
       and under the lgkm-ordered P roundtrip) */                             \
    bf16x8 vf[4][4];                                                          \
    _Pragma("unroll")                                                         \
    for (int ks = 0; ks < 4; ++ks)                                            \
      _Pragma("unroll")                                                       \
      for (int ds = 0; ds < 4; ++ds)                                          \
        vf[ks][ds] = *(const bf16x8*)&Vb[(size_t)((ds * 256 + (jt) * 16 + ks * 4) * 128) + lane * 8]; \
    /* cross-tile K prefetch: issued AFTER vf (in-order vmcnt) */             \
    if ((jt) + 1 < 16) {                                                      \
      _Pragma("unroll")                                                       \
      for (int ks = 0; ks < 2; ++ks)                                          \
        _Pragma("unroll")                                                     \
        for (int js = 0; js < 8; ++js)                                        \
          kn[ks][js] = *(const bf16x8*)&Kb[(size_t)((((jt) + 1) * 64 + js * 8 + ks * 4) * 128) + lane * 8]; \
    }                                                                         \
    /* O += P @ V ; row sums via ones-MFMA on the same A-frags */             \
    __builtin_amdgcn_s_setprio(1);                                            \
    _Pragma("unroll")                                                         \
    for (int ks = 0; ks < 4; ++ks) {                                          \
      const bf16x8 ap0 = *(const bf16x8*)&Pw[cl * 136 + ks * 32 + quad * 8];  \
      const bf16x8 ap1 = *(const bf16x8*)&Pw[(16 + cl) * 136 + ks * 32 + quad * 8]; \
      psum[0] = __builtin_amdgcn_mfma_f32_16x16x32_bf16(ap0, ones8, psum[0], 0, 0, 0); \
      psum[1] = __builtin_amdgcn_mfma_f32_16x16x32_bf16(ap1, ones8, psum[1], 0, 0, 0); \
      _Pragma("unroll")                                                       \
      for (int ds = 0; ds < 4; ++ds) {                                        \
        o[0][ds] = __builtin_amdgcn_mfma_f32_16x16x32_bf16(ap0, vf[ks][ds], o[0][ds], 0, 0, 0); \
        o[1][ds] = __builtin_amdgcn_mfma_f32_16x16x32_bf16(ap1, vf[ks][ds], o[1][ds], 0, 0, 0); \
      }                                                                       \
    }                                                                         \
    __builtin_amdgcn_s_setprio(0);                                            \
  }

  for (int jt = 0; jt < 16; jt += 2) {
    TILE_STEP(jt, kA, kB);            // compute kA, prefetch -> kB
    TILE_STEP(jt + 1, kB, kA);        // compute kB, prefetch -> kA
  }
  #undef TILE_STEP

  // psum rows align with o rows: lane-local normalize, no shuffles
  const int b = bh >> 4, hd = bh & 15;
  #pragma unroll
  for (int h = 0; h < 2; ++h) {
    float inv[4];
    #pragma unroll
    for (int r = 0; r < 4; ++r) inv[r] = __builtin_amdgcn_rcpf(psum[h][r]);
    #pragma unroll
    for (int ds = 0; ds < 4; ++ds)
      #pragma unroll
      for (int r = 0; r < 4; ++r) {
        const int t = q0 + 16 * h + quad * 4 + r;
        const int d = ds * 16 + cl;
        Y[((size_t)b * 2048 + t) * 1024 + hd * 64 + d] = f2bf(o[h][ds][r] * inv[r]);
      }
  }
}

extern "C" void kernel_launch(void* const* d_in, const int* in_sizes, int n_in,
                              void* d_out, int out_size, void* d_ws, size_t ws_size,
                              hipStream_t stream) {
  (void)in_sizes; (void)n_in; (void)out_size; (void)ws_size;
  const float* x  = (const float*)d_in[0];
  const float* Wq = (const float*)d_in[1];
  const float* Wk = (const float*)d_in[2];
  const float* Wv = (const float*)d_in[3];
  const float* Wo = (const float*)d_in[4];

  char* ws = (char*)d_ws;
  const size_t MB = 1024 * 1024;
  u16t* xb  = (u16t*)(ws);               // [4096][1024] bf16 (8 MB) — aliased by Yw
  u16t* Wqb = (u16t*)(ws + 8 * MB);      // Wq/Wk/Wv contiguous -> [3072][1024]
  u16t* Wkb = (u16t*)(ws + 10 * MB);
  u16t* Wvb = (u16t*)(ws + 12 * MB);
  u16t* Wob = (u16t*)(ws + 14 * MB);
  u16t* Qw  = (u16t*)(ws + 16 * MB);     // [32][2048][64] bf16 head-split (pre-scaled)
  u16t* Ktw = (u16t*)(ws + 24 * MB);     // [32] fragment-tiled K'
  u16t* Vtw = (u16t*)(ws + 32 * MB);     // [32] fragment-tiled V'
  u16t* Yw  = xb;                        // safe alias: xb dead after QKV gemm

  convert_bf16<<<8192, 256, 0, stream>>>(x, Wq, Wk, Wv, Wo, xb, Wqb, Wkb, Wvb, Wob);
  // fused QKV: B = [3072][1024], output target selected by n0>>10
  gemm_bt<1><<<dim3(24, 32), 256, 0, stream>>>(
      xb, Wqb, Qw, Ktw, Vtw, 4096, 3072, 1024);
  flash_attn<<<dim3(32, 16), 256, 0, stream>>>(Qw, Ktw, Vtw, Yw);
  gemm_bt<0><<<dim3(8, 32), 256, 0, stream>>>(
      Yw, Wob, d_out, d_out, d_out, 4096, 1024, 1024);
}